// Round 8
// baseline (59.052 us; speedup 1.0000x reference)
//
#include <hip/hip_runtime.h>
#include <hip/hip_bf16.h>

#define DDIM 4096
#define ADIM 21
#define BM   64                 // rows per block
#define KC   256                // k per chunk (1KB/row bursts)
#define NCH  (DDIM / KC)        // 16
#define NTHR 256                // 4 waves

typedef __attribute__((ext_vector_type(8))) short bf16x8;
typedef __attribute__((ext_vector_type(4))) float f32x4;

// LDS: x [64][256] bf16 = 32KB x2, W [32][256] bf16 = 16KB x2 -> 96KB total
#define XOFF(b) ((b) * 32768)
#define WOFF(b) (65536 + (b) * 16384)

// row stride 512B; XOR-swizzle 16B granules (8 rows -> 8 bank-groups, 2-way=free)
__device__ __forceinline__ int swz(int row, int kbyte) {
    return (row * 512 + kbyte) ^ ((row & 7) << 4);
}

__device__ __forceinline__ unsigned pk2(float lo, float hi) {
    unsigned short a = __builtin_bit_cast(unsigned short, __float2bfloat16(lo));
    unsigned short b = __builtin_bit_cast(unsigned short, __float2bfloat16(hi));
    return (unsigned)a | ((unsigned)b << 16);
}

// R6 counted-vmcnt schedule (raw s_barrier + lgkmcnt(0) only; vmcnt never
// drained in-loop), KC=256 so each x row is read in 1KB contiguous bursts
// (DRAM page-locality test) and barrier count halves (18 total).
__global__ __launch_bounds__(NTHR, 1)
void fem_mfma(const float* __restrict__ x,
              const float* __restrict__ v,
              const float* __restrict__ W,
              const float* __restrict__ bias,
              float* __restrict__ result,   // [B]
              float* __restrict__ out)      // [B][ADIM]
{
    __shared__ char smem[98304];
    const int t = threadIdx.x;
    const int rowbase = blockIdx.x * BM;

    float4 xE[16], xO[16], wE[8], wO[8];

    auto issue = [&](int c, float4 (&xr)[16], float4 (&wr)[8]) {
        const int kg8 = (t & 15) * 8;
        const float* xs = x + (size_t)(rowbase + (t >> 4)) * DDIM + c * KC + kg8;
#pragma unroll
        for (int j = 0; j < 4; ++j) {
            const float* s = xs + (size_t)j * 16 * DDIM;
#pragma unroll
            for (int h = 0; h < 2; ++h) {
                xr[4 * j + 2 * h]     = *(const float4*)(s + h * 128);
                xr[4 * j + 2 * h + 1] = *(const float4*)(s + h * 128 + 4);
            }
        }
        const float* ws = W + (size_t)(t >> 4) * DDIM + c * KC + kg8;
#pragma unroll
        for (int h = 0; h < 2; ++h) {
            wr[2 * h]     = *(const float4*)(ws + h * 128);
            wr[2 * h + 1] = *(const float4*)(ws + h * 128 + 4);
        }
        if (t < 80) {                       // W rows 16..20
            const float* w2 = W + (size_t)(16 + (t >> 4)) * DDIM + c * KC + kg8;
#pragma unroll
            for (int h = 0; h < 2; ++h) {
                wr[4 + 2 * h] = *(const float4*)(w2 + h * 128);
                wr[5 + 2 * h] = *(const float4*)(w2 + h * 128 + 4);
            }
        }
    };

    auto write_stage = [&](int buf, const float4 (&xr)[16], const float4 (&wr)[8]) {
        char* xb = smem + XOFF(buf);
        const int kg = t & 15;
#pragma unroll
        for (int j = 0; j < 4; ++j) {
            const int row = (t >> 4) + j * 16;
#pragma unroll
            for (int h = 0; h < 2; ++h) {
                uint4 g;
                g.x = pk2(xr[4 * j + 2 * h].x,     xr[4 * j + 2 * h].y);
                g.y = pk2(xr[4 * j + 2 * h].z,     xr[4 * j + 2 * h].w);
                g.z = pk2(xr[4 * j + 2 * h + 1].x, xr[4 * j + 2 * h + 1].y);
                g.w = pk2(xr[4 * j + 2 * h + 1].z, xr[4 * j + 2 * h + 1].w);
                *(uint4*)(xb + swz(row, (h * 128 + kg * 8) * 2)) = g;
            }
        }
        char* wb = smem + WOFF(buf);
#pragma unroll
        for (int h = 0; h < 2; ++h) {
            uint4 g;
            g.x = pk2(wr[2 * h].x,     wr[2 * h].y);
            g.y = pk2(wr[2 * h].z,     wr[2 * h].w);
            g.z = pk2(wr[2 * h + 1].x, wr[2 * h + 1].y);
            g.w = pk2(wr[2 * h + 1].z, wr[2 * h + 1].w);
            *(uint4*)(wb + swz(t >> 4, (h * 128 + kg * 8) * 2)) = g;
        }
        if (t < 80) {
#pragma unroll
            for (int h = 0; h < 2; ++h) {
                uint4 g;
                g.x = pk2(wr[4 + 2 * h].x, wr[4 + 2 * h].y);
                g.y = pk2(wr[4 + 2 * h].z, wr[4 + 2 * h].w);
                g.z = pk2(wr[5 + 2 * h].x, wr[5 + 2 * h].y);
                g.w = pk2(wr[5 + 2 * h].z, wr[5 + 2 * h].w);
                *(uint4*)(wb + swz(16 + (t >> 4), (h * 128 + kg * 8) * 2)) = g;
            }
        }
    };

    const int lane = t & 63;
    const int wv   = t >> 6;            // wave id, owns 16 rows
    const int a0   = lane & 15;
    const int kh   = (lane >> 4) * 8;

    f32x4 acc0, acc1;
    {
        const float ba0 = bias[a0];
        const float ba1 = (a0 < 5) ? bias[16 + a0] : 0.f;
        acc0 = (f32x4){ba0, ba0, ba0, ba0};
        acc1 = (f32x4){ba1, ba1, ba1, ba1};
    }

    auto compute = [&](int buf) {
        const char* xb = smem + XOFF(buf);
        const char* wb = smem + WOFF(buf);
        const int rowA = wv * 16 + (lane & 15);
#pragma unroll
        for (int k0 = 0; k0 < KC; k0 += 32) {
            bf16x8 a  = *(const bf16x8*)(xb + swz(rowA,    (k0 + kh) * 2));
            bf16x8 b0 = *(const bf16x8*)(wb + swz(a0,      (k0 + kh) * 2));
            bf16x8 b1 = *(const bf16x8*)(wb + swz(16 + a0, (k0 + kh) * 2));
            acc0 = __builtin_amdgcn_mfma_f32_16x16x32_bf16(a, b0, acc0, 0, 0, 0);
            acc1 = __builtin_amdgcn_mfma_f32_16x16x32_bf16(a, b1, acc1, 0, 0, 0);
        }
    };

    auto barrier = [&]() {
        asm volatile("s_waitcnt lgkmcnt(0)" ::: "memory");
        __builtin_amdgcn_s_barrier();
        __builtin_amdgcn_sched_barrier(0);   // rule #18 insurance
    };

    // ---- prologue: zero W rows 21..31 (both buffers, never rewritten) ----
    for (int g = t; g < 352; g += NTHR) {    // 11 rows x 32 granules
        const int row = 21 + (g >> 5), kb = (g & 31) * 16;
        const uint4 z = {0, 0, 0, 0};
        *(uint4*)(smem + WOFF(0) + swz(row, kb)) = z;
        *(uint4*)(smem + WOFF(1) + swz(row, kb)) = z;
    }
    issue(0, xE, wE);
    issue(1, xO, wO);
    write_stage(0, xE, wE);       // chunk 0 (one-time vmcnt stall)
    issue(2, xE, wE);
    barrier();                    // buf0 ready

    // ---- main loop: 2 chunks/iter, 1 barrier/chunk, vmcnt never drained ----
    for (int c = 0; c <= NCH - 4; c += 2) {
        write_stage(1, xO, wO);               // chunk c+1 (issued 1 iter ago)
        issue(c + 3, xO, wO);
        compute(0);                           // chunk c
        barrier();                            // buf1 ready, buf0 free
        write_stage(0, xE, wE);               // chunk c+2
        if (c + 4 < NCH) issue(c + 4, xE, wE);
        compute(1);                           // chunk c+1
        barrier();                            // buf0 ready, buf1 free
    }
    // tail: buf0 has chunk NCH-2, xO holds chunk NCH-1
    write_stage(1, xO, wO);
    compute(0);
    barrier();
    compute(1);

    // ---- epilogue: C/D layout row=(lane>>4)*4+reg, col=lane&15 ----
    // Every output element written exactly once (no atomics, no memset).
    const size_t growbase = (size_t)rowbase + wv * 16 + (lane >> 4) * 4;
#pragma unroll
    for (int r = 0; r < 4; ++r) {
        const size_t row = growbase + r;
        const float o0 = acc0[r];
        out[row * ADIM + a0] = o0;
        float p = o0 * v[row * ADIM + a0];
        if (a0 < 5) {
            const float o1 = acc1[r];
            out[row * ADIM + 16 + a0] = o1;
            p += o1 * v[row * ADIM + 16 + a0];
        }
        p += __shfl_xor(p, 1);
        p += __shfl_xor(p, 2);
        p += __shfl_xor(p, 4);
        p += __shfl_xor(p, 8);
        if (a0 == 0) result[row] = p;
    }
}

extern "C" void kernel_launch(void* const* d_in, const int* in_sizes, int n_in,
                              void* d_out, int out_size, void* d_ws, size_t ws_size,
                              hipStream_t stream) {
    const float* x  = (const float*)d_in[0];
    const float* v  = (const float*)d_in[1];
    const float* W  = (const float*)d_in[2];
    const float* b  = (const float*)d_in[3];

    const int B = in_sizes[0] / DDIM;     // 16384

    float* result = (float*)d_out;        // [B]
    float* out    = (float*)d_out + B;    // [B][ADIM]

    fem_mfma<<<dim3(B / BM), dim3(NTHR), 0, stream>>>(x, v, W, b, result, out);
}

// Round 9
// 56.420 us; speedup vs baseline: 1.0467x; 1.0467x over previous
//
#include <hip/hip_runtime.h>
#include <hip/hip_bf16.h>

#define DDIM 4096
#define ADIM 21
#define BM   64                 // rows per block
#define KC   128                // k per chunk
#define NCH  (DDIM / KC)        // 32
#define NTHR 256                // 4 waves

typedef __attribute__((ext_vector_type(8))) short bf16x8;
typedef __attribute__((ext_vector_type(4))) float f32x4;

// LDS: x tile [64][128] bf16 (16KB) x2, W tile [32][128] bf16 (8KB) x2 = 48KB
#define XOFF(b) ((b) * 16384)
#define WOFF(b) (32768 + (b) * 8192)

// row-major [row][k] bf16, row stride 256B; XOR-swizzle 16B granules
__device__ __forceinline__ int swz(int row, int kbyte) {
    return (row * 256 + kbyte) ^ ((row & 7) << 4);
}

__device__ __forceinline__ unsigned pk2(float lo, float hi) {
    unsigned short a = __builtin_bit_cast(unsigned short, __float2bfloat16(lo));
    unsigned short b = __builtin_bit_cast(unsigned short, __float2bfloat16(hi));
    return (unsigned)a | ((unsigned)b << 16);
}

// FINAL (roofline config, R6): ~258 MB irreducible fp32 x-read at the chip's
// sustainable many-stream read rate (~4.9 TB/s) bounds this kernel at ~55us.
// Schedule/occupancy/burst variants (R4,R5,R7,R8) all confirmed the wall.
// Structure: 1 raw s_barrier per chunk (lgkmcnt(0) only — vmcnt NEVER drained
// in-loop, loads stay in flight across barriers); reg-staged E/O double
// buffer issued 2 chunks ahead; single-writer epilogue, no atomics.
__global__ __launch_bounds__(NTHR, 1)
void fem_mfma(const float* __restrict__ x,
              const float* __restrict__ v,
              const float* __restrict__ W,
              const float* __restrict__ bias,
              float* __restrict__ result,   // [B]
              float* __restrict__ out)      // [B][ADIM]
{
    __shared__ char smem[49152];
    const int t = threadIdx.x;
    const int rowbase = blockIdx.x * BM;

    float4 xE[8], xO[8], wE[4], wO[4];

    auto issue = [&](int c, float4 (&xr)[8], float4 (&wr)[4]) {
        const float* xs = x + (size_t)(rowbase + (t >> 4)) * DDIM + c * KC + (t & 15) * 8;
#pragma unroll
        for (int j = 0; j < 4; ++j) {
            const float* s = xs + (size_t)j * 16 * DDIM;
            xr[2 * j]     = *(const float4*)s;
            xr[2 * j + 1] = *(const float4*)(s + 4);
        }
        const float* ws = W + (size_t)(t >> 4) * DDIM + c * KC + (t & 15) * 8;
        wr[0] = *(const float4*)ws;
        wr[1] = *(const float4*)(ws + 4);
        if (t < 80) {                       // W rows 16..20
            const float* w2 = W + (size_t)(16 + (t >> 4)) * DDIM + c * KC + (t & 15) * 8;
            wr[2] = *(const float4*)w2;
            wr[3] = *(const float4*)(w2 + 4);
        }
    };

    auto write_stage = [&](int buf, const float4 (&xr)[8], const float4 (&wr)[4]) {
        char* xb = smem + XOFF(buf);
        const int kg = t & 15;
#pragma unroll
        for (int j = 0; j < 4; ++j) {
            const int row = (t >> 4) + j * 16;
            uint4 g;
            g.x = pk2(xr[2 * j].x, xr[2 * j].y);
            g.y = pk2(xr[2 * j].z, xr[2 * j].w);
            g.z = pk2(xr[2 * j + 1].x, xr[2 * j + 1].y);
            g.w = pk2(xr[2 * j + 1].z, xr[2 * j + 1].w);
            *(uint4*)(xb + swz(row, kg * 16)) = g;
        }
        char* wb = smem + WOFF(buf);
        {
            uint4 g;
            g.x = pk2(wr[0].x, wr[0].y); g.y = pk2(wr[0].z, wr[0].w);
            g.z = pk2(wr[1].x, wr[1].y); g.w = pk2(wr[1].z, wr[1].w);
            *(uint4*)(wb + swz(t >> 4, kg * 16)) = g;
        }
        if (t < 80) {
            uint4 g;
            g.x = pk2(wr[2].x, wr[2].y); g.y = pk2(wr[2].z, wr[2].w);
            g.z = pk2(wr[3].x, wr[3].y); g.w = pk2(wr[3].z, wr[3].w);
            *(uint4*)(wb + swz(16 + (t >> 4), kg * 16)) = g;
        }
    };

    const int lane = t & 63;
    const int wv   = t >> 6;            // wave id, owns 16 rows
    const int a0   = lane & 15;
    const int kh   = (lane >> 4) * 8;

    f32x4 acc0, acc1;
    {
        const float ba0 = bias[a0];
        const float ba1 = (a0 < 5) ? bias[16 + a0] : 0.f;
        acc0 = (f32x4){ba0, ba0, ba0, ba0};
        acc1 = (f32x4){ba1, ba1, ba1, ba1};
    }

    auto compute = [&](int buf) {
        const char* xb = smem + XOFF(buf);
        const char* wb = smem + WOFF(buf);
        const int rowA = wv * 16 + (lane & 15);
#pragma unroll
        for (int k0 = 0; k0 < KC; k0 += 32) {
            bf16x8 a  = *(const bf16x8*)(xb + swz(rowA,    (k0 + kh) * 2));
            bf16x8 b0 = *(const bf16x8*)(wb + swz(a0,      (k0 + kh) * 2));
            bf16x8 b1 = *(const bf16x8*)(wb + swz(16 + a0, (k0 + kh) * 2));
            acc0 = __builtin_amdgcn_mfma_f32_16x16x32_bf16(a, b0, acc0, 0, 0, 0);
            acc1 = __builtin_amdgcn_mfma_f32_16x16x32_bf16(a, b1, acc1, 0, 0, 0);
        }
    };

    // Raw barrier: drain LDS ops only; global loads stay in flight.
    auto barrier = [&]() {
        asm volatile("s_waitcnt lgkmcnt(0)" ::: "memory");
        __builtin_amdgcn_s_barrier();
        __builtin_amdgcn_sched_barrier(0);   // rule #18 insurance
    };

    // ---- prologue: zero W rows 21..31 (both buffers, never rewritten) ----
    if (t < 176) {
        const int row = 21 + (t >> 4), kg = t & 15;
        const uint4 z = {0, 0, 0, 0};
        *(uint4*)(smem + WOFF(0) + swz(row, kg * 16)) = z;
        *(uint4*)(smem + WOFF(1) + swz(row, kg * 16)) = z;
    }
    issue(0, xE, wE);
    issue(1, xO, wO);
    write_stage(0, xE, wE);       // chunk 0 -> buf0 (one-time vmcnt stall)
    issue(2, xE, wE);             // chunk 2 in flight
    barrier();                    // buf0 ready

    // ---- main loop: 2 chunks/iter, 1 barrier/chunk ----
    for (int c = 0; c <= NCH - 4; c += 2) {
        write_stage(1, xO, wO);               // chunk c+1 (issued 1 iter ago)
        issue(c + 3, xO, wO);                 // c+3 <= NCH-1 always here
        compute(0);                           // chunk c
        barrier();                            // buf1 ready, buf0 free
        write_stage(0, xE, wE);               // chunk c+2
        if (c + 4 < NCH) issue(c + 4, xE, wE);
        compute(1);                           // chunk c+1
        barrier();                            // buf0 ready, buf1 free
    }
    // tail: buf0 has chunk NCH-2, xO holds chunk NCH-1
    write_stage(1, xO, wO);
    compute(0);                               // chunk NCH-2
    barrier();
    compute(1);                               // chunk NCH-1

    // ---- epilogue: C/D layout row=(lane>>4)*4+reg, col=lane&15 ----
    // Every output element written exactly once (no atomics, no memset).
    const size_t growbase = (size_t)rowbase + wv * 16 + (lane >> 4) * 4;
#pragma unroll
    for (int r = 0; r < 4; ++r) {
        const size_t row = growbase + r;
        const float o0 = acc0[r];
        out[row * ADIM + a0] = o0;
        float p = o0 * v[row * ADIM + a0];
        if (a0 < 5) {
            const float o1 = acc1[r];
            out[row * ADIM + 16 + a0] = o1;
            p += o1 * v[row * ADIM + 16 + a0];
        }
        p += __shfl_xor(p, 1);
        p += __shfl_xor(p, 2);
        p += __shfl_xor(p, 4);
        p += __shfl_xor(p, 8);
        if (a0 == 0) result[row] = p;
    }
}

extern "C" void kernel_launch(void* const* d_in, const int* in_sizes, int n_in,
                              void* d_out, int out_size, void* d_ws, size_t ws_size,
                              hipStream_t stream) {
    const float* x  = (const float*)d_in[0];
    const float* v  = (const float*)d_in[1];
    const float* W  = (const float*)d_in[2];
    const float* b  = (const float*)d_in[3];

    const int B = in_sizes[0] / DDIM;     // 16384

    float* result = (float*)d_out;        // [B]
    float* out    = (float*)d_out + B;    // [B][ADIM]

    fem_mfma<<<dim3(B / BM), dim3(NTHR), 0, stream>>>(x, v, W, b, result, out);
}